// Round 1
// baseline (695.632 us; speedup 1.0000x reference)
//
#include <hip/hip_runtime.h>
#include <hip/hip_bf16.h>

#define K_DIM 256   // input feature dim for both layers' GEMM K (256 and 256)

// ---------------------------------------------------------------------------
// CSR build: histogram of dst, exclusive scan, scatter edges by dst.
// ---------------------------------------------------------------------------

__global__ void degree_hist_kernel(const int* __restrict__ dst, int E,
                                   int* __restrict__ cnt) {
    int e = blockIdx.x * blockDim.x + threadIdx.x;
    if (e < E) atomicAdd(&cnt[dst[e]], 1);
}

// Single-block scan: exclusive prefix of cnt -> row_ptr/fill, also dis = rsqrt(cnt+1).
__global__ __launch_bounds__(256) void scan_kernel(const int* __restrict__ cnt,
                                                   int* __restrict__ row_ptr,
                                                   int* __restrict__ fill,
                                                   float* __restrict__ dis, int N) {
    const int T = 256;
    const int t = threadIdx.x;
    const int per = (N + T - 1) / T;
    const int lo = t * per;
    const int hi = min(lo + per, N);

    int sum = 0;
    for (int i = lo; i < hi; ++i) sum += cnt[i];

    __shared__ int s[T];
    s[t] = sum;
    __syncthreads();
    // Hillis-Steele inclusive scan
    for (int off = 1; off < T; off <<= 1) {
        int v = (t >= off) ? s[t - off] : 0;
        __syncthreads();
        s[t] += v;
        __syncthreads();
    }
    int run = (t == 0) ? 0 : s[t - 1];
    for (int i = lo; i < hi; ++i) {
        int c = cnt[i];
        row_ptr[i] = run;
        fill[i] = run;
        dis[i] = rsqrtf((float)(c + 1));
        run += c;
    }
    if (t == T - 1) row_ptr[N] = run;
}

__global__ void build_csr_kernel(const int* __restrict__ src,
                                 const int* __restrict__ dst, int E,
                                 int* __restrict__ fill, int* __restrict__ col) {
    int e = blockIdx.x * blockDim.x + threadIdx.x;
    if (e < E) {
        int d = dst[e];
        int pos = atomicAdd(&fill[d], 1);
        col[pos] = src[e];
    }
}

// ---------------------------------------------------------------------------
// FP32 register-blocked GEMM: C[M,NCOLS] = A[M,256] @ B[256,NCOLS]
// 128x128 tile / block (256 threads), 8x8 per thread, BK=8.
// ---------------------------------------------------------------------------

template <int NCOLS>
__global__ __launch_bounds__(256) void gemm_kernel(const float* __restrict__ A,
                                                   const float* __restrict__ B,
                                                   float* __restrict__ C, int M) {
    __shared__ float As[8][132];  // [k][row], padded
    __shared__ float Bs[8][132];  // [k][col], padded

    const int t = threadIdx.x;
    const int tx = t & 15;   // col group 0..15
    const int ty = t >> 4;   // row group 0..15
    const int m0 = blockIdx.y * 128;
    const int n0 = blockIdx.x * 128;

    const int ar = t >> 1;         // 0..127 (row within A tile)
    const int ak = (t & 1) * 4;    // 0 or 4
    const int bk = t >> 5;         // 0..7
    const int bc = (t & 31) * 4;   // 0..124

    float acc[8][8];
#pragma unroll
    for (int i = 0; i < 8; ++i)
#pragma unroll
        for (int j = 0; j < 8; ++j) acc[i][j] = 0.f;

    for (int k0 = 0; k0 < K_DIM; k0 += 8) {
        float4 av = make_float4(0.f, 0.f, 0.f, 0.f);
        const int grow = m0 + ar;
        if (grow < M) av = *(const float4*)(A + (size_t)grow * K_DIM + k0 + ak);
        const float4 bv = *(const float4*)(B + (size_t)(k0 + bk) * NCOLS + n0 + bc);

        __syncthreads();  // protect LDS from previous iteration's readers
        As[ak + 0][ar] = av.x;
        As[ak + 1][ar] = av.y;
        As[ak + 2][ar] = av.z;
        As[ak + 3][ar] = av.w;
        *(float4*)&Bs[bk][bc] = bv;
        __syncthreads();

#pragma unroll
        for (int k = 0; k < 8; ++k) {
            float a[8], b[8];
            *(float4*)&a[0] = *(const float4*)&As[k][ty * 8];
            *(float4*)&a[4] = *(const float4*)&As[k][ty * 8 + 4];
            *(float4*)&b[0] = *(const float4*)&Bs[k][tx * 8];
            *(float4*)&b[4] = *(const float4*)&Bs[k][tx * 8 + 4];
#pragma unroll
            for (int i = 0; i < 8; ++i)
#pragma unroll
                for (int j = 0; j < 8; ++j) acc[i][j] += a[i] * b[j];
        }
    }

#pragma unroll
    for (int i = 0; i < 8; ++i) {
        const int row = m0 + ty * 8 + i;
        if (row < M) {
            float4 v0 = make_float4(acc[i][0], acc[i][1], acc[i][2], acc[i][3]);
            float4 v1 = make_float4(acc[i][4], acc[i][5], acc[i][6], acc[i][7]);
            *(float4*)(C + (size_t)row * NCOLS + n0 + tx * 8) = v0;
            *(float4*)(C + (size_t)row * NCOLS + n0 + tx * 8 + 4) = v1;
        }
    }
}

// ---------------------------------------------------------------------------
// CSR aggregation: one wave per dst node, 64 lanes cover F features (VEC each).
// out[n] = sum_{e in CSR[n]} xw[src_e] * dis[src_e]*dis[n]  +  xw[n]*dis[n]^2 + bias
// Optional ReLU.
// ---------------------------------------------------------------------------

template <int F, bool RELU>
__global__ __launch_bounds__(256) void aggregate_kernel(
    const float* __restrict__ xw, const int* __restrict__ row_ptr,
    const int* __restrict__ col, const float* __restrict__ dis,
    const float* __restrict__ bias, float* __restrict__ out, int N) {
    constexpr int VEC = F / 64;  // floats per lane (4 for F=256, 2 for F=128)
    const int wid = threadIdx.x >> 6;
    const int lane = threadIdx.x & 63;
    const int n = blockIdx.x * 4 + wid;
    if (n >= N) return;

    const float dn = dis[n];
    float acc[VEC];
    {   // self-loop: weight = dis[n]^2
        const float w = dn * dn;
        const float* xn = xw + (size_t)n * F + lane * VEC;
#pragma unroll
        for (int v = 0; v < VEC; ++v) acc[v] = xn[v] * w;
    }

    const int e0 = row_ptr[n];
    const int e1 = row_ptr[n + 1];
    for (int e = e0; e < e1; ++e) {
        const int s = col[e];
        const float w = dis[s] * dn;
        const float* xs = xw + (size_t)s * F + lane * VEC;
        if (VEC == 4) {
            float4 v = *(const float4*)xs;
            acc[0] += v.x * w;
            acc[1] += v.y * w;
            acc[2] += v.z * w;
            acc[3] += v.w * w;
        } else {
            float2 v = *(const float2*)xs;
            acc[0] += v.x * w;
            acc[1] += v.y * w;
        }
    }

    float* o = out + (size_t)n * F + lane * VEC;
#pragma unroll
    for (int v = 0; v < VEC; ++v) {
        float r = acc[v] + bias[lane * VEC + v];
        if (RELU) r = fmaxf(r, 0.f);
        o[v] = r;
    }
}

// ---------------------------------------------------------------------------
// Launch
// ---------------------------------------------------------------------------

extern "C" void kernel_launch(void* const* d_in, const int* in_sizes, int n_in,
                              void* d_out, int out_size, void* d_ws, size_t ws_size,
                              hipStream_t stream) {
    const float* x = (const float*)d_in[0];
    const int* edge = (const int*)d_in[1];
    const float* W1 = (const float*)d_in[2];
    const float* b1 = (const float*)d_in[3];
    const float* W2 = (const float*)d_in[4];
    const float* b2 = (const float*)d_in[5];

    const int N = in_sizes[0] / 256;   // 50000
    const int E = in_sizes[1] / 2;     // 800000
    const int* src = edge;
    const int* dst = edge + E;

    // workspace carve (256B aligned)
    char* w = (char*)d_ws;
    auto carve = [&](size_t bytes) {
        char* p = w;
        w += (bytes + 255) & ~(size_t)255;
        return p;
    };
    int* cnt = (int*)carve((size_t)N * 4);
    int* row_ptr = (int*)carve((size_t)(N + 1) * 4);
    int* fill = (int*)carve((size_t)N * 4);
    int* col = (int*)carve((size_t)E * 4);
    float* dis = (float*)carve((size_t)N * 4);
    float* xw1 = (float*)carve((size_t)N * 256 * 4);
    float* h = (float*)carve((size_t)N * 256 * 4);
    float* xw2 = xw1;  // alias: xw1 dead after aggregate1

    float* out = (float*)d_out;

    hipMemsetAsync(cnt, 0, (size_t)N * 4, stream);

    const int eblocks = (E + 255) / 256;
    degree_hist_kernel<<<eblocks, 256, 0, stream>>>(dst, E, cnt);
    scan_kernel<<<1, 256, 0, stream>>>(cnt, row_ptr, fill, dis, N);
    build_csr_kernel<<<eblocks, 256, 0, stream>>>(src, dst, E, fill, col);

    // layer 1: xw1 = x @ W1  [N,256]
    {
        dim3 grid(256 / 128, (N + 127) / 128);
        gemm_kernel<256><<<grid, 256, 0, stream>>>(x, W1, xw1, N);
    }
    aggregate_kernel<256, true><<<(N + 3) / 4, 256, 0, stream>>>(
        xw1, row_ptr, col, dis, b1, h, N);

    // layer 2: xw2 = h @ W2  [N,128]
    {
        dim3 grid(128 / 128, (N + 127) / 128);
        gemm_kernel<128><<<grid, 256, 0, stream>>>(h, W2, xw2, N);
    }
    aggregate_kernel<128, false><<<(N + 3) / 4, 256, 0, stream>>>(
        xw2, row_ptr, col, dis, b2, out, N);
}

// Round 2
// 518.135 us; speedup vs baseline: 1.3426x; 1.3426x over previous
//
#include <hip/hip_runtime.h>
#include <hip/hip_bf16.h>

#define K_DIM 256   // input feature dim for both layers' GEMM K (256 and 256)

// ---------------------------------------------------------------------------
// CSR build: histogram of dst, 3-phase device-wide scan, scatter edges by dst.
// ---------------------------------------------------------------------------

__global__ void degree_hist_kernel(const int* __restrict__ dst, int E,
                                   int* __restrict__ cnt) {
    int e = blockIdx.x * blockDim.x + threadIdx.x;
    if (e < E) atomicAdd(&cnt[dst[e]], 1);
}

constexpr int SCAN_C = 512;  // cnt elements per scan block (2 per thread)

// Phase 1: per-block sums of cnt.
__global__ __launch_bounds__(256) void scan_phase1(const int* __restrict__ cnt,
                                                   int* __restrict__ bsum, int N) {
    const int t = threadIdx.x;
    const int i0 = blockIdx.x * SCAN_C + 2 * t;
    int s = 0;
    if (i0 < N) s += cnt[i0];
    if (i0 + 1 < N) s += cnt[i0 + 1];
    __shared__ int sh[256];
    sh[t] = s;
    __syncthreads();
    for (int off = 128; off > 0; off >>= 1) {
        if (t < off) sh[t] += sh[t + off];
        __syncthreads();
    }
    if (t == 0) bsum[blockIdx.x] = sh[0];
}

// Phase 2: single-block exclusive scan of block sums (nb <= 256); writes total.
__global__ __launch_bounds__(256) void scan_phase2(int* __restrict__ bsum, int nb,
                                                   int* __restrict__ row_ptr, int N) {
    const int t = threadIdx.x;
    int v = (t < nb) ? bsum[t] : 0;
    __shared__ int sh[256];
    sh[t] = v;
    __syncthreads();
    for (int off = 1; off < 256; off <<= 1) {
        int u = (t >= off) ? sh[t - off] : 0;
        __syncthreads();
        sh[t] += u;
        __syncthreads();
    }
    if (t < nb) bsum[t] = (t == 0) ? 0 : sh[t - 1];
    if (t == 255) row_ptr[N] = sh[255];
}

// Phase 3: per-block local exclusive scan + block offset; writes row_ptr, fill, dis.
__global__ __launch_bounds__(256) void scan_phase3(const int* __restrict__ cnt,
                                                   const int* __restrict__ bsum,
                                                   int* __restrict__ row_ptr,
                                                   int* __restrict__ fill,
                                                   float* __restrict__ dis, int N) {
    const int t = threadIdx.x;
    const int i0 = blockIdx.x * SCAN_C + 2 * t;
    const int c0 = (i0 < N) ? cnt[i0] : 0;
    const int c1 = (i0 + 1 < N) ? cnt[i0 + 1] : 0;
    __shared__ int sh[256];
    sh[t] = c0 + c1;
    __syncthreads();
    for (int off = 1; off < 256; off <<= 1) {
        int u = (t >= off) ? sh[t - off] : 0;
        __syncthreads();
        sh[t] += u;
        __syncthreads();
    }
    const int excl = ((t == 0) ? 0 : sh[t - 1]) + bsum[blockIdx.x];
    if (i0 < N) {
        row_ptr[i0] = excl;
        fill[i0] = excl;
        dis[i0] = rsqrtf((float)(c0 + 1));
    }
    if (i0 + 1 < N) {
        row_ptr[i0 + 1] = excl + c0;
        fill[i0 + 1] = excl + c0;
        dis[i0 + 1] = rsqrtf((float)(c1 + 1));
    }
}

// Scatter edges by dst; also precompute per-edge weight wnorm = dis[s]*dis[d]
// so the aggregation loop reads a SEQUENTIAL weight array instead of a random
// dis gather.
__global__ void build_csr_kernel(const int* __restrict__ src,
                                 const int* __restrict__ dst, int E,
                                 int* __restrict__ fill, int* __restrict__ col,
                                 const float* __restrict__ dis,
                                 float* __restrict__ wnorm) {
    int e = blockIdx.x * blockDim.x + threadIdx.x;
    if (e < E) {
        int s = src[e];
        int d = dst[e];
        int pos = atomicAdd(&fill[d], 1);
        col[pos] = s;
        wnorm[pos] = dis[s] * dis[d];
    }
}

// ---------------------------------------------------------------------------
// FP32 register-blocked GEMM: C[M,NCOLS] = A[M,256] @ B[256,NCOLS]
// 128x128 tile / block (256 threads), 8x8 per thread, BK=8.
// ---------------------------------------------------------------------------

template <int NCOLS>
__global__ __launch_bounds__(256) void gemm_kernel(const float* __restrict__ A,
                                                   const float* __restrict__ B,
                                                   float* __restrict__ C, int M) {
    __shared__ float As[8][132];  // [k][row], padded
    __shared__ float Bs[8][132];  // [k][col], padded

    const int t = threadIdx.x;
    const int tx = t & 15;   // col group 0..15
    const int ty = t >> 4;   // row group 0..15
    const int m0 = blockIdx.y * 128;
    const int n0 = blockIdx.x * 128;

    const int ar = t >> 1;         // 0..127 (row within A tile)
    const int ak = (t & 1) * 4;    // 0 or 4
    const int bk = t >> 5;         // 0..7
    const int bc = (t & 31) * 4;   // 0..124

    float acc[8][8];
#pragma unroll
    for (int i = 0; i < 8; ++i)
#pragma unroll
        for (int j = 0; j < 8; ++j) acc[i][j] = 0.f;

    for (int k0 = 0; k0 < K_DIM; k0 += 8) {
        float4 av = make_float4(0.f, 0.f, 0.f, 0.f);
        const int grow = m0 + ar;
        if (grow < M) av = *(const float4*)(A + (size_t)grow * K_DIM + k0 + ak);
        const float4 bv = *(const float4*)(B + (size_t)(k0 + bk) * NCOLS + n0 + bc);

        __syncthreads();  // protect LDS from previous iteration's readers
        As[ak + 0][ar] = av.x;
        As[ak + 1][ar] = av.y;
        As[ak + 2][ar] = av.z;
        As[ak + 3][ar] = av.w;
        *(float4*)&Bs[bk][bc] = bv;
        __syncthreads();

#pragma unroll
        for (int k = 0; k < 8; ++k) {
            float a[8], b[8];
            *(float4*)&a[0] = *(const float4*)&As[k][ty * 8];
            *(float4*)&a[4] = *(const float4*)&As[k][ty * 8 + 4];
            *(float4*)&b[0] = *(const float4*)&Bs[k][tx * 8];
            *(float4*)&b[4] = *(const float4*)&Bs[k][tx * 8 + 4];
#pragma unroll
            for (int i = 0; i < 8; ++i)
#pragma unroll
                for (int j = 0; j < 8; ++j) acc[i][j] += a[i] * b[j];
        }
    }

#pragma unroll
    for (int i = 0; i < 8; ++i) {
        const int row = m0 + ty * 8 + i;
        if (row < M) {
            float4 v0 = make_float4(acc[i][0], acc[i][1], acc[i][2], acc[i][3]);
            float4 v1 = make_float4(acc[i][4], acc[i][5], acc[i][6], acc[i][7]);
            *(float4*)(C + (size_t)row * NCOLS + n0 + tx * 8) = v0;
            *(float4*)(C + (size_t)row * NCOLS + n0 + tx * 8 + 4) = v1;
        }
    }
}

// ---------------------------------------------------------------------------
// CSR aggregation: one wave per dst node, 64 lanes cover F features (VEC each).
// out[n] = sum_{e in CSR[n]} xw[col_e] * wnorm[e]  +  xw[n]*dis[n]^2 + bias
// Edge loop unrolled x2 for memory-level parallelism.
// ---------------------------------------------------------------------------

template <int F, bool RELU>
__global__ __launch_bounds__(256) void aggregate_kernel(
    const float* __restrict__ xw, const int* __restrict__ row_ptr,
    const int* __restrict__ col, const float* __restrict__ wnorm,
    const float* __restrict__ dis, const float* __restrict__ bias,
    float* __restrict__ out, int N) {
    constexpr int VEC = F / 64;  // floats per lane (4 for F=256, 2 for F=128)
    const int wid = threadIdx.x >> 6;
    const int lane = threadIdx.x & 63;
    const int n = blockIdx.x * 4 + wid;
    if (n >= N) return;

    const float dn = dis[n];
    float acc[VEC];
    {   // self-loop: weight = dis[n]^2
        const float w = dn * dn;
        const float* xn = xw + (size_t)n * F + lane * VEC;
#pragma unroll
        for (int v = 0; v < VEC; ++v) acc[v] = xn[v] * w;
    }

    const int e0 = row_ptr[n];
    const int e1 = row_ptr[n + 1];
    int e = e0;
    for (; e + 2 <= e1; e += 2) {
        const int s0 = col[e];
        const int s1 = col[e + 1];
        const float w0 = wnorm[e];
        const float w1 = wnorm[e + 1];
        const float* x0 = xw + (size_t)s0 * F + lane * VEC;
        const float* x1 = xw + (size_t)s1 * F + lane * VEC;
        if (VEC == 4) {
            const float4 v0 = *(const float4*)x0;
            const float4 v1 = *(const float4*)x1;
            acc[0] += v0.x * w0 + v1.x * w1;
            acc[1] += v0.y * w0 + v1.y * w1;
            acc[2] += v0.z * w0 + v1.z * w1;
            acc[3] += v0.w * w0 + v1.w * w1;
        } else {
            const float2 v0 = *(const float2*)x0;
            const float2 v1 = *(const float2*)x1;
            acc[0] += v0.x * w0 + v1.x * w1;
            acc[1] += v0.y * w0 + v1.y * w1;
        }
    }
    if (e < e1) {
        const int s0 = col[e];
        const float w0 = wnorm[e];
        const float* x0 = xw + (size_t)s0 * F + lane * VEC;
        if (VEC == 4) {
            const float4 v0 = *(const float4*)x0;
            acc[0] += v0.x * w0;
            acc[1] += v0.y * w0;
            acc[2] += v0.z * w0;
            acc[3] += v0.w * w0;
        } else {
            const float2 v0 = *(const float2*)x0;
            acc[0] += v0.x * w0;
            acc[1] += v0.y * w0;
        }
    }

    float* o = out + (size_t)n * F + lane * VEC;
#pragma unroll
    for (int v = 0; v < VEC; ++v) {
        float r = acc[v] + bias[lane * VEC + v];
        if (RELU) r = fmaxf(r, 0.f);
        o[v] = r;
    }
}

// ---------------------------------------------------------------------------
// Launch
// ---------------------------------------------------------------------------

extern "C" void kernel_launch(void* const* d_in, const int* in_sizes, int n_in,
                              void* d_out, int out_size, void* d_ws, size_t ws_size,
                              hipStream_t stream) {
    const float* x = (const float*)d_in[0];
    const int* edge = (const int*)d_in[1];
    const float* W1 = (const float*)d_in[2];
    const float* b1 = (const float*)d_in[3];
    const float* W2 = (const float*)d_in[4];
    const float* b2 = (const float*)d_in[5];

    const int N = in_sizes[0] / 256;   // 50000
    const int E = in_sizes[1] / 2;     // 800000
    const int* src = edge;
    const int* dst = edge + E;

    // workspace carve (256B aligned)
    char* w = (char*)d_ws;
    auto carve = [&](size_t bytes) {
        char* p = w;
        w += (bytes + 255) & ~(size_t)255;
        return p;
    };
    const int nscan = (N + SCAN_C - 1) / SCAN_C;   // 98 blocks
    int* cnt = (int*)carve((size_t)N * 4);
    int* row_ptr = (int*)carve((size_t)(N + 1) * 4);
    int* fill = (int*)carve((size_t)N * 4);
    int* col = (int*)carve((size_t)E * 4);
    float* wnorm = (float*)carve((size_t)E * 4);
    float* dis = (float*)carve((size_t)N * 4);
    int* bsum = (int*)carve((size_t)nscan * 4);
    float* xw1 = (float*)carve((size_t)N * 256 * 4);
    float* h = (float*)carve((size_t)N * 256 * 4);
    float* xw2 = xw1;  // alias: xw1 dead after aggregate1

    float* out = (float*)d_out;

    hipMemsetAsync(cnt, 0, (size_t)N * 4, stream);

    const int eblocks = (E + 255) / 256;
    degree_hist_kernel<<<eblocks, 256, 0, stream>>>(dst, E, cnt);
    scan_phase1<<<nscan, 256, 0, stream>>>(cnt, bsum, N);
    scan_phase2<<<1, 256, 0, stream>>>(bsum, nscan, row_ptr, N);
    scan_phase3<<<nscan, 256, 0, stream>>>(cnt, bsum, row_ptr, fill, dis, N);
    build_csr_kernel<<<eblocks, 256, 0, stream>>>(src, dst, E, fill, col, dis, wnorm);

    // layer 1: xw1 = x @ W1  [N,256]
    {
        dim3 grid(256 / 128, (N + 127) / 128);
        gemm_kernel<256><<<grid, 256, 0, stream>>>(x, W1, xw1, N);
    }
    aggregate_kernel<256, true><<<(N + 3) / 4, 256, 0, stream>>>(
        xw1, row_ptr, col, wnorm, dis, b1, h, N);

    // layer 2: xw2 = h @ W2  [N,128]
    {
        dim3 grid(128 / 128, (N + 127) / 128);
        gemm_kernel<128><<<grid, 256, 0, stream>>>(h, W2, xw2, N);
    }
    aggregate_kernel<128, false><<<(N + 3) / 4, 256, 0, stream>>>(
        xw2, row_ptr, col, wnorm, dis, b2, out, N);
}

// Round 7
// 424.966 us; speedup vs baseline: 1.6369x; 1.2192x over previous
//
#include <hip/hip_runtime.h>
#include <hip/hip_bf16.h>

#define K_DIM 256   // GEMM K for both layers

typedef __attribute__((ext_vector_type(8))) short short8;
typedef __attribute__((ext_vector_type(4))) float f32x4;

// ---------------------------------------------------------------------------
// CSR build: histogram of dst, 3-phase device-wide scan, scatter edges by dst.
// ---------------------------------------------------------------------------

__global__ void degree_hist_kernel(const int* __restrict__ dst, int E,
                                   int* __restrict__ cnt) {
    int e = blockIdx.x * blockDim.x + threadIdx.x;
    if (e < E) atomicAdd(&cnt[dst[e]], 1);
}

constexpr int SCAN_C = 512;  // cnt elements per scan block (2 per thread)

__global__ __launch_bounds__(256) void scan_phase1(const int* __restrict__ cnt,
                                                   int* __restrict__ bsum, int N) {
    const int t = threadIdx.x;
    const int i0 = blockIdx.x * SCAN_C + 2 * t;
    int s = 0;
    if (i0 < N) s += cnt[i0];
    if (i0 + 1 < N) s += cnt[i0 + 1];
    __shared__ int sh[256];
    sh[t] = s;
    __syncthreads();
    for (int off = 128; off > 0; off >>= 1) {
        if (t < off) sh[t] += sh[t + off];
        __syncthreads();
    }
    if (t == 0) bsum[blockIdx.x] = sh[0];
}

__global__ __launch_bounds__(256) void scan_phase2(int* __restrict__ bsum, int nb,
                                                   int* __restrict__ row_ptr, int N) {
    const int t = threadIdx.x;
    int v = (t < nb) ? bsum[t] : 0;
    __shared__ int sh[256];
    sh[t] = v;
    __syncthreads();
    for (int off = 1; off < 256; off <<= 1) {
        int u = (t >= off) ? sh[t - off] : 0;
        __syncthreads();
        sh[t] += u;
        __syncthreads();
    }
    if (t < nb) bsum[t] = (t == 0) ? 0 : sh[t - 1];
    if (t == 255) row_ptr[N] = sh[255];
}

__global__ __launch_bounds__(256) void scan_phase3(const int* __restrict__ cnt,
                                                   const int* __restrict__ bsum,
                                                   int* __restrict__ row_ptr,
                                                   int* __restrict__ fill,
                                                   float* __restrict__ dis, int N) {
    const int t = threadIdx.x;
    const int i0 = blockIdx.x * SCAN_C + 2 * t;
    const int c0 = (i0 < N) ? cnt[i0] : 0;
    const int c1 = (i0 + 1 < N) ? cnt[i0 + 1] : 0;
    __shared__ int sh[256];
    sh[t] = c0 + c1;
    __syncthreads();
    for (int off = 1; off < 256; off <<= 1) {
        int u = (t >= off) ? sh[t - off] : 0;
        __syncthreads();
        sh[t] += u;
        __syncthreads();
    }
    const int excl = ((t == 0) ? 0 : sh[t - 1]) + bsum[blockIdx.x];
    if (i0 < N) {
        row_ptr[i0] = excl;
        fill[i0] = excl;
        dis[i0] = rsqrtf((float)(c0 + 1));
    }
    if (i0 + 1 < N) {
        row_ptr[i0 + 1] = excl + c0;
        fill[i0 + 1] = excl + c0;
        dis[i0 + 1] = rsqrtf((float)(c1 + 1));
    }
}

__global__ void build_csr_kernel(const int* __restrict__ src,
                                 const int* __restrict__ dst, int E,
                                 int* __restrict__ fill, int* __restrict__ col,
                                 const float* __restrict__ dis,
                                 float* __restrict__ wnorm) {
    int e = blockIdx.x * blockDim.x + threadIdx.x;
    if (e < E) {
        int s = src[e];
        int d = dst[e];
        int pos = atomicAdd(&fill[d], 1);
        col[pos] = s;
        wnorm[pos] = dis[s] * dis[d];
    }
}

// ---------------------------------------------------------------------------
// MFMA bf16x3 (split-fp32) GEMM: C[M,NCOLS] = A[M,256] @ B[256,NCOLS], fp32 io.
// a = hi + lo (bf16 each); C = Ahi*Bhi + Ahi*Blo + Alo*Bhi, fp32 accumulate.
// Tile 128x128, BK=32, 4 waves (2x2), each wave 64x64 = 4x4 fragments of
// mfma_f32_16x16x32_bf16. LDS row stride 40 elems (80 B) => ds_read_b128
// fragment reads are 2-way-conflict-free (free).
// ---------------------------------------------------------------------------

__device__ __forceinline__ unsigned short bf16_hi(float v) {
    __hip_bfloat16 h = __float2bfloat16(v);
    return *(unsigned short*)&h;
}
__device__ __forceinline__ float bf16_back(unsigned short u) {
    __hip_bfloat16 h = *(__hip_bfloat16*)&u;
    return __bfloat162float(h);
}

template <int NCOLS>
__global__ __launch_bounds__(256) void gemm_mfma_kernel(const float* __restrict__ A,
                                                        const float* __restrict__ B,
                                                        float* __restrict__ C, int M) {
    __shared__ unsigned short As_hi[128][40];
    __shared__ unsigned short As_lo[128][40];
    __shared__ unsigned short Bs_hi[128][40];  // B transposed: [col][k]
    __shared__ unsigned short Bs_lo[128][40];

    const int t = threadIdx.x;
    const int lane = t & 63;
    const int wid = t >> 6;
    const int wm = wid >> 1;        // 0..1
    const int wn = wid & 1;         // 0..1
    const int m0 = blockIdx.y * 128;
    const int n0 = blockIdx.x * 128;

    f32x4 acc[4][4];
#pragma unroll
    for (int i = 0; i < 4; ++i)
#pragma unroll
        for (int j = 0; j < 4; ++j) acc[i][j] = (f32x4)(0.f);

    // staging coords
    const int a_r = t >> 3;        // 0..31 (+32 per pass)
    const int a_c4 = t & 7;        // float4 index within 32-wide k
    const int b_col = t & 127;     // 0..127
    const int b_kq0 = t >> 7;      // 0..1 (+2 per pass)

    for (int k0 = 0; k0 < K_DIM; k0 += 32) {
        __syncthreads();  // previous iteration's readers done

        // ---- stage A: 128 rows x 32 k (fp32 -> bf16 hi/lo) ----
#pragma unroll
        for (int p = 0; p < 4; ++p) {
            const int row = a_r + p * 32;
            const int grow = min(m0 + row, M - 1);
            const float4 v = *(const float4*)(A + (size_t)grow * K_DIM + k0 + a_c4 * 4);
            unsigned short h0 = bf16_hi(v.x), h1 = bf16_hi(v.y),
                           h2 = bf16_hi(v.z), h3 = bf16_hi(v.w);
            unsigned short l0 = bf16_hi(v.x - bf16_back(h0)),
                           l1 = bf16_hi(v.y - bf16_back(h1)),
                           l2 = bf16_hi(v.z - bf16_back(h2)),
                           l3 = bf16_hi(v.w - bf16_back(h3));
            *(ushort4*)&As_hi[row][a_c4 * 4] = make_ushort4(h0, h1, h2, h3);
            *(ushort4*)&As_lo[row][a_c4 * 4] = make_ushort4(l0, l1, l2, l3);
        }

        // ---- stage B transposed: [col][k], 128 cols x 32 k ----
#pragma unroll
        for (int p = 0; p < 4; ++p) {
            const int kq = b_kq0 + p * 2;  // 0..7
            float v0 = B[(size_t)(k0 + kq * 4 + 0) * NCOLS + n0 + b_col];
            float v1 = B[(size_t)(k0 + kq * 4 + 1) * NCOLS + n0 + b_col];
            float v2 = B[(size_t)(k0 + kq * 4 + 2) * NCOLS + n0 + b_col];
            float v3 = B[(size_t)(k0 + kq * 4 + 3) * NCOLS + n0 + b_col];
            unsigned short h0 = bf16_hi(v0), h1 = bf16_hi(v1),
                           h2 = bf16_hi(v2), h3 = bf16_hi(v3);
            unsigned short l0 = bf16_hi(v0 - bf16_back(h0)),
                           l1 = bf16_hi(v1 - bf16_back(h1)),
                           l2 = bf16_hi(v2 - bf16_back(h2)),
                           l3 = bf16_hi(v3 - bf16_back(h3));
            *(ushort4*)&Bs_hi[b_col][kq * 4] = make_ushort4(h0, h1, h2, h3);
            *(ushort4*)&Bs_lo[b_col][kq * 4] = make_ushort4(l0, l1, l2, l3);
        }

        __syncthreads();

        // ---- fragments: lane holds row/col = l&15, k = (l>>4)*8 .. +7 ----
        const int fr = lane & 15;
        const int fk = (lane >> 4) * 8;
        short8 a_hi[4], a_lo[4], b_hi[4], b_lo[4];
#pragma unroll
        for (int fm = 0; fm < 4; ++fm) {
            const int r = wm * 64 + fm * 16 + fr;
            a_hi[fm] = *(const short8*)&As_hi[r][fk];
            a_lo[fm] = *(const short8*)&As_lo[r][fk];
        }
#pragma unroll
        for (int fn = 0; fn < 4; ++fn) {
            const int c = wn * 64 + fn * 16 + fr;
            b_hi[fn] = *(const short8*)&Bs_hi[c][fk];
            b_lo[fn] = *(const short8*)&Bs_lo[c][fk];
        }

#pragma unroll
        for (int fm = 0; fm < 4; ++fm)
#pragma unroll
            for (int fn = 0; fn < 4; ++fn) {
                acc[fm][fn] = __builtin_amdgcn_mfma_f32_16x16x32_bf16(
                    a_hi[fm], b_hi[fn], acc[fm][fn], 0, 0, 0);
                acc[fm][fn] = __builtin_amdgcn_mfma_f32_16x16x32_bf16(
                    a_hi[fm], b_lo[fn], acc[fm][fn], 0, 0, 0);
                acc[fm][fn] = __builtin_amdgcn_mfma_f32_16x16x32_bf16(
                    a_lo[fm], b_hi[fn], acc[fm][fn], 0, 0, 0);
            }
    }

    // ---- epilogue: C/D layout col = lane&15, row = (lane>>4)*4 + r ----
    const int c_col = n0 + wn * 64 + (lane & 15);
    const int r_base = m0 + wm * 64 + (lane >> 4) * 4;
#pragma unroll
    for (int fm = 0; fm < 4; ++fm)
#pragma unroll
        for (int fn = 0; fn < 4; ++fn)
#pragma unroll
            for (int r = 0; r < 4; ++r) {
                const int row = r_base + fm * 16 + r;
                if (row < M)
                    C[(size_t)row * NCOLS + c_col + fn * 16] = acc[fm][fn][r];
            }
}

// ---------------------------------------------------------------------------
// CSR aggregation: one wave per dst node, 64 lanes cover F features (VEC each).
// out[n] = sum_e xw[col_e]*wnorm[e] + xw[n]*dis[n]^2 + bias ; optional ReLU.
// ---------------------------------------------------------------------------

template <int F, bool RELU>
__global__ __launch_bounds__(256) void aggregate_kernel(
    const float* __restrict__ xw, const int* __restrict__ row_ptr,
    const int* __restrict__ col, const float* __restrict__ wnorm,
    const float* __restrict__ dis, const float* __restrict__ bias,
    float* __restrict__ out, int N) {
    constexpr int VEC = F / 64;
    const int wid = threadIdx.x >> 6;
    const int lane = threadIdx.x & 63;
    const int n = blockIdx.x * 4 + wid;
    if (n >= N) return;

    const float dn = dis[n];
    float acc[VEC];
    {
        const float w = dn * dn;
        const float* xn = xw + (size_t)n * F + lane * VEC;
#pragma unroll
        for (int v = 0; v < VEC; ++v) acc[v] = xn[v] * w;
    }

    const int e0 = row_ptr[n];
    const int e1 = row_ptr[n + 1];
    int e = e0;
    for (; e + 2 <= e1; e += 2) {
        const int s0 = col[e];
        const int s1 = col[e + 1];
        const float w0 = wnorm[e];
        const float w1 = wnorm[e + 1];
        const float* x0 = xw + (size_t)s0 * F + lane * VEC;
        const float* x1 = xw + (size_t)s1 * F + lane * VEC;
        if (VEC == 4) {
            const float4 v0 = *(const float4*)x0;
            const float4 v1 = *(const float4*)x1;
            acc[0] += v0.x * w0 + v1.x * w1;
            acc[1] += v0.y * w0 + v1.y * w1;
            acc[2] += v0.z * w0 + v1.z * w1;
            acc[3] += v0.w * w0 + v1.w * w1;
        } else {
            const float2 v0 = *(const float2*)x0;
            const float2 v1 = *(const float2*)x1;
            acc[0] += v0.x * w0 + v1.x * w1;
            acc[1] += v0.y * w0 + v1.y * w1;
        }
    }
    if (e < e1) {
        const int s0 = col[e];
        const float w0 = wnorm[e];
        const float* x0 = xw + (size_t)s0 * F + lane * VEC;
        if (VEC == 4) {
            const float4 v0 = *(const float4*)x0;
            acc[0] += v0.x * w0;
            acc[1] += v0.y * w0;
            acc[2] += v0.z * w0;
            acc[3] += v0.w * w0;
        } else {
            const float2 v0 = *(const float2*)x0;
            acc[0] += v0.x * w0;
            acc[1] += v0.y * w0;
        }
    }

    float* o = out + (size_t)n * F + lane * VEC;
#pragma unroll
    for (int v = 0; v < VEC; ++v) {
        float r = acc[v] + bias[lane * VEC + v];
        if (RELU) r = fmaxf(r, 0.f);
        o[v] = r;
    }
}

// ---------------------------------------------------------------------------
// Launch
// ---------------------------------------------------------------------------

extern "C" void kernel_launch(void* const* d_in, const int* in_sizes, int n_in,
                              void* d_out, int out_size, void* d_ws, size_t ws_size,
                              hipStream_t stream) {
    const float* x = (const float*)d_in[0];
    const int* edge = (const int*)d_in[1];
    const float* W1 = (const float*)d_in[2];
    const float* b1 = (const float*)d_in[3];
    const float* W2 = (const float*)d_in[4];
    const float* b2 = (const float*)d_in[5];

    const int N = in_sizes[0] / 256;   // 50000
    const int E = in_sizes[1] / 2;     // 800000
    const int* src = edge;
    const int* dst = edge + E;

    char* w = (char*)d_ws;
    auto carve = [&](size_t bytes) {
        char* p = w;
        w += (bytes + 255) & ~(size_t)255;
        return p;
    };
    const int nscan = (N + SCAN_C - 1) / SCAN_C;
    int* cnt = (int*)carve((size_t)N * 4);
    int* row_ptr = (int*)carve((size_t)(N + 1) * 4);
    int* fill = (int*)carve((size_t)N * 4);
    int* col = (int*)carve((size_t)E * 4);
    float* wnorm = (float*)carve((size_t)E * 4);
    float* dis = (float*)carve((size_t)N * 4);
    int* bsum = (int*)carve((size_t)nscan * 4);
    float* xw1 = (float*)carve((size_t)N * 256 * 4);
    float* h = (float*)carve((size_t)N * 256 * 4);
    float* xw2 = xw1;  // alias: xw1 dead after aggregate1

    float* out = (float*)d_out;

    hipMemsetAsync(cnt, 0, (size_t)N * 4, stream);

    const int eblocks = (E + 255) / 256;
    degree_hist_kernel<<<eblocks, 256, 0, stream>>>(dst, E, cnt);
    scan_phase1<<<nscan, 256, 0, stream>>>(cnt, bsum, N);
    scan_phase2<<<1, 256, 0, stream>>>(bsum, nscan, row_ptr, N);
    scan_phase3<<<nscan, 256, 0, stream>>>(cnt, bsum, row_ptr, fill, dis, N);
    build_csr_kernel<<<eblocks, 256, 0, stream>>>(src, dst, E, fill, col, dis, wnorm);

    // layer 1: xw1 = x @ W1  [N,256]
    {
        dim3 grid(256 / 128, (N + 127) / 128);
        gemm_mfma_kernel<256><<<grid, 256, 0, stream>>>(x, W1, xw1, N);
    }
    aggregate_kernel<256, true><<<(N + 3) / 4, 256, 0, stream>>>(
        xw1, row_ptr, col, wnorm, dis, b1, h, N);

    // layer 2: xw2 = h @ W2  [N,128]
    {
        dim3 grid(128 / 128, (N + 127) / 128);
        gemm_mfma_kernel<128><<<grid, 256, 0, stream>>>(h, W2, xw2, N);
    }
    aggregate_kernel<128, false><<<(N + 3) / 4, 256, 0, stream>>>(
        xw2, row_ptr, col, wnorm, dis, b2, out, N);
}

// Round 8
// 366.036 us; speedup vs baseline: 1.9004x; 1.1610x over previous
//
#include <hip/hip_runtime.h>
#include <hip/hip_bf16.h>

#define K_DIM 256   // GEMM K for both layers

typedef __attribute__((ext_vector_type(8))) short short8;
typedef __attribute__((ext_vector_type(4))) float f32x4;

// ---------------------------------------------------------------------------
// CSR build: histogram of dst, 3-phase device-wide scan, scatter edges by dst.
// ---------------------------------------------------------------------------

__global__ void degree_hist_kernel(const int* __restrict__ dst, int E,
                                   int* __restrict__ cnt) {
    int e = blockIdx.x * blockDim.x + threadIdx.x;
    if (e < E) atomicAdd(&cnt[dst[e]], 1);
}

constexpr int SCAN_C = 512;  // cnt elements per scan block (2 per thread)

__global__ __launch_bounds__(256) void scan_phase1(const int* __restrict__ cnt,
                                                   int* __restrict__ bsum, int N) {
    const int t = threadIdx.x;
    const int i0 = blockIdx.x * SCAN_C + 2 * t;
    int s = 0;
    if (i0 < N) s += cnt[i0];
    if (i0 + 1 < N) s += cnt[i0 + 1];
    __shared__ int sh[256];
    sh[t] = s;
    __syncthreads();
    for (int off = 128; off > 0; off >>= 1) {
        if (t < off) sh[t] += sh[t + off];
        __syncthreads();
    }
    if (t == 0) bsum[blockIdx.x] = sh[0];
}

__global__ __launch_bounds__(256) void scan_phase2(int* __restrict__ bsum, int nb,
                                                   int* __restrict__ row_ptr, int N) {
    const int t = threadIdx.x;
    int v = (t < nb) ? bsum[t] : 0;
    __shared__ int sh[256];
    sh[t] = v;
    __syncthreads();
    for (int off = 1; off < 256; off <<= 1) {
        int u = (t >= off) ? sh[t - off] : 0;
        __syncthreads();
        sh[t] += u;
        __syncthreads();
    }
    if (t < nb) bsum[t] = (t == 0) ? 0 : sh[t - 1];
    if (t == 255) row_ptr[N] = sh[255];
}

__global__ __launch_bounds__(256) void scan_phase3(const int* __restrict__ cnt,
                                                   const int* __restrict__ bsum,
                                                   int* __restrict__ row_ptr,
                                                   int* __restrict__ fill,
                                                   float* __restrict__ dis, int N) {
    const int t = threadIdx.x;
    const int i0 = blockIdx.x * SCAN_C + 2 * t;
    const int c0 = (i0 < N) ? cnt[i0] : 0;
    const int c1 = (i0 + 1 < N) ? cnt[i0 + 1] : 0;
    __shared__ int sh[256];
    sh[t] = c0 + c1;
    __syncthreads();
    for (int off = 1; off < 256; off <<= 1) {
        int u = (t >= off) ? sh[t - off] : 0;
        __syncthreads();
        sh[t] += u;
        __syncthreads();
    }
    const int excl = ((t == 0) ? 0 : sh[t - 1]) + bsum[blockIdx.x];
    if (i0 < N) {
        row_ptr[i0] = excl;
        fill[i0] = excl;
        dis[i0] = rsqrtf((float)(c0 + 1));
    }
    if (i0 + 1 < N) {
        row_ptr[i0 + 1] = excl + c0;
        fill[i0 + 1] = excl + c0;
        dis[i0 + 1] = rsqrtf((float)(c1 + 1));
    }
}

__global__ void build_csr_kernel(const int* __restrict__ src,
                                 const int* __restrict__ dst, int E,
                                 int* __restrict__ fill, int* __restrict__ col,
                                 const float* __restrict__ dis,
                                 float* __restrict__ wnorm) {
    int e = blockIdx.x * blockDim.x + threadIdx.x;
    if (e < E) {
        int s = src[e];
        int d = dst[e];
        int pos = atomicAdd(&fill[d], 1);
        col[pos] = s;
        wnorm[pos] = dis[s] * dis[d];
    }
}

// ---------------------------------------------------------------------------
// bf16 helpers
// ---------------------------------------------------------------------------

__device__ __forceinline__ unsigned short bf16_hi(float v) {
    __hip_bfloat16 h = __float2bfloat16(v);
    return *(unsigned short*)&h;
}
__device__ __forceinline__ float bf16_back(unsigned short u) {
    __hip_bfloat16 h = *(__hip_bfloat16*)&u;
    return __bfloat162float(h);
}
__device__ __forceinline__ float bf2f(unsigned short u) {
    unsigned int b = ((unsigned int)u) << 16;
    float f;
    __builtin_memcpy(&f, &b, 4);
    return f;
}

// ---------------------------------------------------------------------------
// MFMA bf16x3 (split-fp32) GEMM: C[M,NCOLS] = A[M,256] @ B[256,NCOLS], fp32 in.
// a = hi + lo (bf16 each); C = Ahi*Bhi + Ahi*Blo + Alo*Bhi, fp32 accumulate.
// Tile 128x128, BK=32, 4 waves (2x2), each wave 64x64 = 4x4 fragments of
// mfma_f32_16x16x32_bf16. LDS row stride 40 elems (80 B).
// Output: bf16 (the aggregation gathers it; halves gather+write traffic).
// ---------------------------------------------------------------------------

template <int NCOLS>
__global__ __launch_bounds__(256) void gemm_mfma_kernel(const float* __restrict__ A,
                                                        const float* __restrict__ B,
                                                        unsigned short* __restrict__ C,
                                                        int M) {
    __shared__ unsigned short As_hi[128][40];
    __shared__ unsigned short As_lo[128][40];
    __shared__ unsigned short Bs_hi[128][40];  // B transposed: [col][k]
    __shared__ unsigned short Bs_lo[128][40];

    const int t = threadIdx.x;
    const int lane = t & 63;
    const int wid = t >> 6;
    const int wm = wid >> 1;        // 0..1
    const int wn = wid & 1;         // 0..1
    const int m0 = blockIdx.y * 128;
    const int n0 = blockIdx.x * 128;

    f32x4 acc[4][4];
#pragma unroll
    for (int i = 0; i < 4; ++i)
#pragma unroll
        for (int j = 0; j < 4; ++j) acc[i][j] = (f32x4)(0.f);

    // staging coords
    const int a_r = t >> 3;        // 0..31 (+32 per pass)
    const int a_c4 = t & 7;        // float4 index within 32-wide k
    const int b_col = t & 127;     // 0..127
    const int b_kq0 = t >> 7;      // 0..1 (+2 per pass)

    for (int k0 = 0; k0 < K_DIM; k0 += 32) {
        __syncthreads();  // previous iteration's readers done

        // ---- stage A: 128 rows x 32 k (fp32 -> bf16 hi/lo) ----
#pragma unroll
        for (int p = 0; p < 4; ++p) {
            const int row = a_r + p * 32;
            const int grow = min(m0 + row, M - 1);
            const float4 v = *(const float4*)(A + (size_t)grow * K_DIM + k0 + a_c4 * 4);
            unsigned short h0 = bf16_hi(v.x), h1 = bf16_hi(v.y),
                           h2 = bf16_hi(v.z), h3 = bf16_hi(v.w);
            unsigned short l0 = bf16_hi(v.x - bf16_back(h0)),
                           l1 = bf16_hi(v.y - bf16_back(h1)),
                           l2 = bf16_hi(v.z - bf16_back(h2)),
                           l3 = bf16_hi(v.w - bf16_back(h3));
            *(ushort4*)&As_hi[row][a_c4 * 4] = make_ushort4(h0, h1, h2, h3);
            *(ushort4*)&As_lo[row][a_c4 * 4] = make_ushort4(l0, l1, l2, l3);
        }

        // ---- stage B transposed: [col][k], 128 cols x 32 k ----
#pragma unroll
        for (int p = 0; p < 4; ++p) {
            const int kq = b_kq0 + p * 2;  // 0..7
            float v0 = B[(size_t)(k0 + kq * 4 + 0) * NCOLS + n0 + b_col];
            float v1 = B[(size_t)(k0 + kq * 4 + 1) * NCOLS + n0 + b_col];
            float v2 = B[(size_t)(k0 + kq * 4 + 2) * NCOLS + n0 + b_col];
            float v3 = B[(size_t)(k0 + kq * 4 + 3) * NCOLS + n0 + b_col];
            unsigned short h0 = bf16_hi(v0), h1 = bf16_hi(v1),
                           h2 = bf16_hi(v2), h3 = bf16_hi(v3);
            unsigned short l0 = bf16_hi(v0 - bf16_back(h0)),
                           l1 = bf16_hi(v1 - bf16_back(h1)),
                           l2 = bf16_hi(v2 - bf16_back(h2)),
                           l3 = bf16_hi(v3 - bf16_back(h3));
            *(ushort4*)&Bs_hi[b_col][kq * 4] = make_ushort4(h0, h1, h2, h3);
            *(ushort4*)&Bs_lo[b_col][kq * 4] = make_ushort4(l0, l1, l2, l3);
        }

        __syncthreads();

        // ---- fragments: lane holds row/col = l&15, k = (l>>4)*8 .. +7 ----
        const int fr = lane & 15;
        const int fk = (lane >> 4) * 8;
        short8 a_hi[4], a_lo[4], b_hi[4], b_lo[4];
#pragma unroll
        for (int fm = 0; fm < 4; ++fm) {
            const int r = wm * 64 + fm * 16 + fr;
            a_hi[fm] = *(const short8*)&As_hi[r][fk];
            a_lo[fm] = *(const short8*)&As_lo[r][fk];
        }
#pragma unroll
        for (int fn = 0; fn < 4; ++fn) {
            const int c = wn * 64 + fn * 16 + fr;
            b_hi[fn] = *(const short8*)&Bs_hi[c][fk];
            b_lo[fn] = *(const short8*)&Bs_lo[c][fk];
        }

#pragma unroll
        for (int fm = 0; fm < 4; ++fm)
#pragma unroll
            for (int fn = 0; fn < 4; ++fn) {
                acc[fm][fn] = __builtin_amdgcn_mfma_f32_16x16x32_bf16(
                    a_hi[fm], b_hi[fn], acc[fm][fn], 0, 0, 0);
                acc[fm][fn] = __builtin_amdgcn_mfma_f32_16x16x32_bf16(
                    a_hi[fm], b_lo[fn], acc[fm][fn], 0, 0, 0);
                acc[fm][fn] = __builtin_amdgcn_mfma_f32_16x16x32_bf16(
                    a_lo[fm], b_hi[fn], acc[fm][fn], 0, 0, 0);
            }
    }

    // ---- epilogue: C/D layout col = lane&15, row = (lane>>4)*4 + r ----
    const int c_col = n0 + wn * 64 + (lane & 15);
    const int r_base = m0 + wm * 64 + (lane >> 4) * 4;
#pragma unroll
    for (int fm = 0; fm < 4; ++fm)
#pragma unroll
        for (int fn = 0; fn < 4; ++fn)
#pragma unroll
            for (int r = 0; r < 4; ++r) {
                const int row = r_base + fm * 16 + r;
                if (row < M)
                    C[(size_t)row * NCOLS + c_col + fn * 16] = bf16_hi(acc[fm][fn][r]);
            }
}

// ---------------------------------------------------------------------------
// CSR aggregation over bf16 features: one wave per dst node, 64 lanes cover F.
// out[n] = sum_e xw[col_e]*wnorm[e] + xw[n]*dis[n]^2 + bias ; optional ReLU.
// xw is bf16 (halved gather traffic); accumulate fp32; out fp32.
// ---------------------------------------------------------------------------

template <int F, bool RELU>
__global__ __launch_bounds__(256) void aggregate_kernel(
    const unsigned short* __restrict__ xw, const int* __restrict__ row_ptr,
    const int* __restrict__ col, const float* __restrict__ wnorm,
    const float* __restrict__ dis, const float* __restrict__ bias,
    float* __restrict__ out, int N) {
    constexpr int VEC = F / 64;  // bf16 elems per lane (4 for F=256, 2 for F=128)
    const int wid = threadIdx.x >> 6;
    const int lane = threadIdx.x & 63;
    const int n = blockIdx.x * 4 + wid;
    if (n >= N) return;

    const float dn = dis[n];
    float acc[VEC];
    {   // self-loop: weight = dis[n]^2
        const float w = dn * dn;
        const unsigned short* xn = xw + (size_t)n * F + lane * VEC;
        if (VEC == 4) {
            const ushort4 u = *(const ushort4*)xn;
            acc[0] = bf2f(u.x) * w;
            acc[1] = bf2f(u.y) * w;
            acc[2] = bf2f(u.z) * w;
            acc[3] = bf2f(u.w) * w;
        } else {
            const ushort2 u = *(const ushort2*)xn;
            acc[0] = bf2f(u.x) * w;
            acc[1] = bf2f(u.y) * w;
        }
    }

    const int e0 = row_ptr[n];
    const int e1 = row_ptr[n + 1];
    int e = e0;
    for (; e + 2 <= e1; e += 2) {
        const int s0 = col[e];
        const int s1 = col[e + 1];
        const float w0 = wnorm[e];
        const float w1 = wnorm[e + 1];
        const unsigned short* x0 = xw + (size_t)s0 * F + lane * VEC;
        const unsigned short* x1 = xw + (size_t)s1 * F + lane * VEC;
        if (VEC == 4) {
            const ushort4 u0 = *(const ushort4*)x0;
            const ushort4 u1 = *(const ushort4*)x1;
            acc[0] += bf2f(u0.x) * w0 + bf2f(u1.x) * w1;
            acc[1] += bf2f(u0.y) * w0 + bf2f(u1.y) * w1;
            acc[2] += bf2f(u0.z) * w0 + bf2f(u1.z) * w1;
            acc[3] += bf2f(u0.w) * w0 + bf2f(u1.w) * w1;
        } else {
            const ushort2 u0 = *(const ushort2*)x0;
            const ushort2 u1 = *(const ushort2*)x1;
            acc[0] += bf2f(u0.x) * w0 + bf2f(u1.x) * w1;
            acc[1] += bf2f(u0.y) * w0 + bf2f(u1.y) * w1;
        }
    }
    if (e < e1) {
        const int s0 = col[e];
        const float w0 = wnorm[e];
        const unsigned short* x0 = xw + (size_t)s0 * F + lane * VEC;
        if (VEC == 4) {
            const ushort4 u0 = *(const ushort4*)x0;
            acc[0] += bf2f(u0.x) * w0;
            acc[1] += bf2f(u0.y) * w0;
            acc[2] += bf2f(u0.z) * w0;
            acc[3] += bf2f(u0.w) * w0;
        } else {
            const ushort2 u0 = *(const ushort2*)x0;
            acc[0] += bf2f(u0.x) * w0;
            acc[1] += bf2f(u0.y) * w0;
        }
    }

    float* o = out + (size_t)n * F + lane * VEC;
#pragma unroll
    for (int v = 0; v < VEC; ++v) {
        float r = acc[v] + bias[lane * VEC + v];
        if (RELU) r = fmaxf(r, 0.f);
        o[v] = r;
    }
}

// ---------------------------------------------------------------------------
// Launch
// ---------------------------------------------------------------------------

extern "C" void kernel_launch(void* const* d_in, const int* in_sizes, int n_in,
                              void* d_out, int out_size, void* d_ws, size_t ws_size,
                              hipStream_t stream) {
    const float* x = (const float*)d_in[0];
    const int* edge = (const int*)d_in[1];
    const float* W1 = (const float*)d_in[2];
    const float* b1 = (const float*)d_in[3];
    const float* W2 = (const float*)d_in[4];
    const float* b2 = (const float*)d_in[5];

    const int N = in_sizes[0] / 256;   // 50000
    const int E = in_sizes[1] / 2;     // 800000
    const int* src = edge;
    const int* dst = edge + E;

    char* w = (char*)d_ws;
    auto carve = [&](size_t bytes) {
        char* p = w;
        w += (bytes + 255) & ~(size_t)255;
        return p;
    };
    const int nscan = (N + SCAN_C - 1) / SCAN_C;
    int* cnt = (int*)carve((size_t)N * 4);
    int* row_ptr = (int*)carve((size_t)(N + 1) * 4);
    int* fill = (int*)carve((size_t)N * 4);
    int* col = (int*)carve((size_t)E * 4);
    float* wnorm = (float*)carve((size_t)E * 4);
    float* dis = (float*)carve((size_t)N * 4);
    int* bsum = (int*)carve((size_t)nscan * 4);
    unsigned short* xw1 = (unsigned short*)carve((size_t)N * 256 * 2);  // bf16
    float* h = (float*)carve((size_t)N * 256 * 4);                      // fp32
    unsigned short* xw2 = xw1;  // alias: xw1 dead after aggregate1 (bf16, smaller)

    float* out = (float*)d_out;

    hipMemsetAsync(cnt, 0, (size_t)N * 4, stream);

    const int eblocks = (E + 255) / 256;
    degree_hist_kernel<<<eblocks, 256, 0, stream>>>(dst, E, cnt);
    scan_phase1<<<nscan, 256, 0, stream>>>(cnt, bsum, N);
    scan_phase2<<<1, 256, 0, stream>>>(bsum, nscan, row_ptr, N);
    scan_phase3<<<nscan, 256, 0, stream>>>(cnt, bsum, row_ptr, fill, dis, N);
    build_csr_kernel<<<eblocks, 256, 0, stream>>>(src, dst, E, fill, col, dis, wnorm);

    // layer 1: xw1 = bf16(x @ W1)  [N,256]
    {
        dim3 grid(256 / 128, (N + 127) / 128);
        gemm_mfma_kernel<256><<<grid, 256, 0, stream>>>(x, W1, xw1, N);
    }
    aggregate_kernel<256, true><<<(N + 3) / 4, 256, 0, stream>>>(
        xw1, row_ptr, col, wnorm, dis, b1, h, N);

    // layer 2: xw2 = bf16(h @ W2)  [N,128]
    {
        dim3 grid(128 / 128, (N + 127) / 128);
        gemm_mfma_kernel<128><<<grid, 256, 0, stream>>>(h, W2, xw2, N);
    }
    aggregate_kernel<128, false><<<(N + 3) / 4, 256, 0, stream>>>(
        xw2, row_ptr, col, wnorm, dis, b2, out, N);
}